// Round 11
// baseline (122.312 us; speedup 1.0000x reference)
//
#include <hip/hip_runtime.h>
#include <math.h>

#define W 131072
#define FR 63                 // floats per pose3d frame (3*21)
#define FPB 32                // frames per block
#define BLKT 256              // 4 waves
#define NBLOCKS (W / FPB)     // 4096
#define STG4 536              // float4 slots staged (2144 floats >= 34 frames)
#define POSE_LAST 2079        // floats available in last block (33 frames)
#define SMOOTH_TOT ((W - 1) * FR)
#define NPAIR 1008            // 16*63 smooth output-pairs per block

__global__ __launch_bounds__(BLKT, 6) void loss_pass1(
    const float* __restrict__ pose3d,
    const float* __restrict__ cam,
    const float* __restrict__ p2d,
    const float* __restrict__ blen,
    const float* __restrict__ ldir,
    const int* __restrict__ bcon,
    const int* __restrict__ lcon,
    float* __restrict__ partial)
{
  __shared__ float sP[STG4 * 4];   // 8576 B
  __shared__ float sCam[FPB * 6];  // 768 B
  __shared__ float sBlen[20];
  __shared__ int   sBC[40], sLC[40];
  __shared__ int   sFlag;
  __shared__ float sWave[4];

  const int tid = threadIdx.x;
  const int blk = blockIdx.x;
  const int f0 = blk * FPB;
  const float* src = pose3d + (size_t)f0 * FR;

  // ---- prefetch single-use global operands into registers (pre-barrier) ----
  int   jp[3]; bool vp[3]; float pd_a[3], pd_b[3]; int fpz[3];
  int   bb[3]; bool vb[3]; float lda[3], ldb[3], ldc[3]; int fbz[3];
#pragma unroll
  for (int k = 0; k < 3; ++k) {
    int t = tid + k * BLKT;
    vp[k] = (t < FPB * 21);
    int tt = vp[k] ? t : 0;
    int f = tt / 21, j = tt - 21 * f;
    fpz[k] = f; jp[k] = j;
    const float* pr = p2d + (size_t)(f0 + f) * 42;
    pd_a[k] = pr[j];
    pd_b[k] = pr[21 + j];

    vb[k] = (t < FPB * 20);
    int tb = vb[k] ? t : 0;
    int f2 = tb / 20, b = tb - 20 * f2;
    fbz[k] = f2; bb[k] = b;
    const float* lr = ldir + (size_t)(f0 + f2) * 60;
    lda[k] = lr[b]; ldb[k] = lr[20 + b]; ldc[k] = lr[40 + b];
  }

  // ---- stage pose tile (34 frames), aligned float4 -> b128 ----
  {
    const float4* g4 = (const float4*)src;
    float4* s4 = (float4*)sP;
    if (blk != NBLOCKS - 1) {
#pragma unroll
      for (int it = 0; it < 3; ++it) {
        int q = tid + it * BLKT;
        if (q < STG4) s4[q] = g4[q];
      }
    } else {
#pragma unroll
      for (int it = 0; it < 3; ++it) {
        int q = tid + it * BLKT;
        if (q < STG4) {
          int j = 4 * q;
          if (j + 4 <= POSE_LAST) s4[q] = g4[q];
          else {
#pragma unroll
            for (int k = 0; k < 4; ++k)
              sP[j + k] = (j + k < POSE_LAST) ? src[j + k] : 0.0f;
          }
        }
      }
    }
  }
  // cam tile + tables + chain check (pre-barrier)
  if (tid < 48) ((float4*)sCam)[tid] = ((const float4*)(cam + (size_t)f0 * 6))[tid];
  bool bad = false;
  if (tid >= 64 && tid < 84) {
    int b = tid - 64;
    int bx = bcon[2 * b], by = bcon[2 * b + 1];
    int lx = lcon[2 * b], ly = lcon[2 * b + 1];
    sBC[2 * b] = bx; sBC[2 * b + 1] = by;
    sLC[2 * b] = lx; sLC[2 * b + 1] = ly;
    bad = !(bx == b + 1 && by == b && lx == b + 1 && ly == b);
  }
  unsigned long long ball = __ballot(bad);
  if (tid == 64) sFlag = (ball == 0ULL) ? 1 : 0;
  if (tid >= 128 && tid < 148) sBlen[tid - 128] = blen[tid - 128];
  __syncthreads();

  const int chain = sFlag;   // broadcast read, block-uniform
  float acc_smooth = 0.0f, acc_proj = 0.0f, acc_bone = 0.0f, acc_lift = 0.0f;

  // ---- smooth: paired outputs (o, o+63) -> 2x ds_read2_b32 per pair ----
  {
    const int lim = (blk == NBLOCKS - 1) ? (SMOOTH_TOT - f0 * FR) : (FPB * FR);
#pragma unroll
    for (int k = 0; k < 4; ++k) {
      int p = tid + k * BLKT;
      if (p < NPAIR) {
        int m = p / 63;
        int o = p + 63 * m;          // = 126*m + r; o+189 <= 2141 < 2144 staged
        const float* q = sP + o;
        float x0 = q[0], x1 = q[63], x2 = q[126], x3 = q[189];
        if (o < lim)      { float d = x2 - 2.0f * x1 + x0; acc_smooth += d * d; }
        if (o + 63 < lim) { float d = x3 - 2.0f * x2 + x1; acc_smooth += d * d; }
      }
    }
  }

  // ---- projection: consume prefetched p2d; pose + cam from LDS ----
#pragma unroll
  for (int k = 0; k < 3; ++k) {
    if (vp[k]) {
      int f = fpz[k], j = jp[k];
      const float* P1 = sP + FR * (f + 1) + j;
      float x = P1[0], y = P1[21], z = P1[42];
      const float* cp = sCam + 6 * f;
      float c0 = cp[0], c1 = cp[1], c2 = cp[2], c3 = cp[3], c4 = cp[4], c5 = cp[5];
      float d0 = c0 * x + c1 * y + c2 * z - pd_a[k];
      float d1 = c3 * x + c4 * y + c5 * z - pd_b[k];
      acc_proj += d0 * d0 + d1 * d1;
    }
  }

  // ---- lift + bone: chain fast-path (3x ds_read2_b32), slow path fallback ----
  if (chain) {
#pragma unroll
    for (int k = 0; k < 3; ++k) {
      if (vb[k]) {
        int f = fbz[k], b = bb[k];
        const float* q = sP + FR * (f + 1) + b;
        float j0 = q[0],  j1 = q[1];
        float k0 = q[21], k1 = q[22];
        float m0 = q[42], m1 = q[43];
        float dx = j1 - j0, dy = k1 - k0, dz = m1 - m0;
        float S = dx * dx + dy * dy + dz * dz;
        float inv = rsqrtf(S);
        float ex = lda[k] - dx * inv;
        float ey = ldb[k] - dy * inv;
        float ez = ldc[k] - dz * inv;
        acc_lift += ex * ex + ey * ey + ez * ez;
        float tt = S - sBlen[b];
        acc_bone += tt * tt;
      }
    }
  } else {
#pragma unroll
    for (int k = 0; k < 3; ++k) {
      if (vb[k]) {
        int f = fbz[k], b = bb[k];
        const float* P1 = sP + FR * (f + 1);
        int lcx = sLC[2 * b], lcy = sLC[2 * b + 1];
        float dx = P1[lcx]      - P1[lcy];
        float dy = P1[21 + lcx] - P1[21 + lcy];
        float dz = P1[42 + lcx] - P1[42 + lcy];
        float S = dx * dx + dy * dy + dz * dz;
        float inv = rsqrtf(S);
        float ex = lda[k] - dx * inv;
        float ey = ldb[k] - dy * inv;
        float ez = ldc[k] - dz * inv;
        acc_lift += ex * ex + ey * ey + ez * ez;
        int bcx = sBC[2 * b], bcy = sBC[2 * b + 1];
        float Sb = S;
        if (bcx != lcx || bcy != lcy) {
          float bx = P1[bcx]      - P1[bcy];
          float by = P1[21 + bcx] - P1[21 + bcy];
          float bz = P1[42 + bcx] - P1[42 + bcy];
          Sb = bx * bx + by * by + bz * bz;
        }
        float tt = Sb - sBlen[b];
        acc_bone += tt * tt;
      }
    }
  }
  // frame 0's bone term (block 0, threads 0..19; generic via sBC)
  if (blk == 0 && tid < 20) {
    int b = tid;
    int bcx = sBC[2 * b], bcy = sBC[2 * b + 1];
    float bx = sP[bcx]      - sP[bcy];
    float by = sP[21 + bcx] - sP[21 + bcy];
    float bz = sP[42 + bcx] - sP[42 + bcy];
    float S0 = bx * bx + by * by + bz * bz;
    float t0 = S0 - sBlen[b];
    acc_bone += t0 * t0;
  }

  // ---- weighted combine + block reduction (4 waves) ----
  float tot = acc_proj * (1.0f / 42.0f) + acc_bone * (1.0f / 20.0f)
            + acc_smooth * (0.5f / 63.0f) + acc_lift * (0.1f / 63.0f);
#pragma unroll
  for (int off = 32; off > 0; off >>= 1) tot += __shfl_xor(tot, off, 64);
  if ((tid & 63) == 0) sWave[tid >> 6] = tot;
  __syncthreads();
  if (tid == 0) partial[blk] = (sWave[0] + sWave[1]) + (sWave[2] + sWave[3]);
}

__global__ __launch_bounds__(256) void loss_pass2(
    const float* __restrict__ partial, float* __restrict__ out)
{
  __shared__ float sW[4];
  int tid = threadIdx.x;
  float s = 0.0f;
#pragma unroll
  for (int i = 0; i < NBLOCKS / 256; ++i) s += partial[i * 256 + tid];
#pragma unroll
  for (int off = 32; off > 0; off >>= 1) s += __shfl_xor(s, off, 64);
  if ((tid & 63) == 0) sW[tid >> 6] = s;
  __syncthreads();
  if (tid == 0) {
    float t = 0.0f;
#pragma unroll
    for (int i = 0; i < 4; ++i) t += sW[i];
    out[0] = t;
  }
}

extern "C" void kernel_launch(void* const* d_in, const int* in_sizes, int n_in,
                              void* d_out, int out_size, void* d_ws, size_t ws_size,
                              hipStream_t stream) {
  const float* pose3d = (const float*)d_in[0];
  const float* cam    = (const float*)d_in[1];
  const float* p2d    = (const float*)d_in[2];
  const float* blen   = (const float*)d_in[3];
  const float* ldir   = (const float*)d_in[4];
  const int*   bcon   = (const int*)d_in[5];
  const int*   lcon   = (const int*)d_in[6];
  float* out     = (float*)d_out;
  float* partial = (float*)d_ws;   // 4096 floats = 16 KB

  loss_pass1<<<NBLOCKS, BLKT, 0, stream>>>(pose3d, cam, p2d, blen, ldir,
                                           bcon, lcon, partial);
  loss_pass2<<<1, 256, 0, stream>>>(partial, out);
}